// Round 6
// baseline (515.980 us; speedup 1.0000x reference)
//
#include <hip/hip_runtime.h>
#include <hip/hip_fp16.h>

#define T_DIM 2048
#define D_DIM 256
#define K_CODES 512
#define N_ROWS 131072
#define Q_ELEMS 33554432
#define FMARGIN 2.0e-4f

typedef __attribute__((ext_vector_type(8))) _Float16 f16x8;
typedef __attribute__((ext_vector_type(4))) float f32x4;

// ws layout (bytes):
// [0, 2048)        norms (512 f32, numpy-pairwise-exact)
// [2048, 18432)    bsums (2048 f64)
// [20480, 36864)   flag bitmap (4096 u32; bit n = row n)
// [36864, 299008)  e16: f16(512*e) [512][256]  (only if ws fits)

__device__ __forceinline__ float comb8(const float r[8]) {
  return ((r[0] + r[1]) + (r[2] + r[3])) + ((r[4] + r[5]) + (r[6] + r[7]));
}

// norms (numpy-pairwise exact), e16 image, bitmap clear
__global__ __launch_bounds__(256) void vq_prep(const float* __restrict__ e,
                                               float* __restrict__ norms,
                                               unsigned short* __restrict__ e16,
                                               unsigned* __restrict__ bitmap,
                                               int use_ws) {
  __shared__ float srow[D_DIM];
  int k = blockIdx.x, t = threadIdx.x;
  float v = e[k * D_DIM + t];
  srow[t] = v;
  if (use_ws) e16[k * D_DIM + t] = __half_as_ushort(__float2half(512.0f * v));
  if (t < 8) bitmap[k * 8 + t] = 0u;
  __syncthreads();
  if (t == 0) {
    float res[2];
    #pragma unroll
    for (int h = 0; h < 2; ++h) {
      float r[8];
      #pragma unroll
      for (int j = 0; j < 8; ++j) { float a = srow[h * 128 + j]; r[j] = __fmul_rn(a, a); }
      for (int i = 8; i < 128; i += 8)
        #pragma unroll
        for (int j = 0; j < 8; ++j) { float a = srow[h * 128 + i + j]; r[j] = __fadd_rn(r[j], __fmul_rn(a, a)); }
      res[h] = comb8(r);
    }
    norms[k] = __fadd_rn(res[0], res[1]);
  }
}

template <int USE_WS>
__global__ __launch_bounds__(256, 2) void vq_main(
    const float* __restrict__ x, const float* __restrict__ e,
    const float* __restrict__ norms, const unsigned short* __restrict__ e16,
    float* __restrict__ out_q, float* __restrict__ out_idx,
    double* __restrict__ bsums, unsigned* __restrict__ bitmap) {
  __shared__ unsigned short xlds[64 * 256];  // 32 KB, [row t][k d] chunk-swizzled
  __shared__ float nlds[K_CODES];
  __shared__ float wmin[4][64], wm2[4][64];
  __shared__ int   wid[4][64];
  __shared__ float rmin[64];
  __shared__ int   widx[64];
  __shared__ unsigned lflag[2];
  __shared__ double dred[4];

  const int tx = threadIdx.x;
  const int blk = blockIdx.x;                // 2048
  const int b = blk >> 5, t0 = (blk & 31) * 64;
  const int lane = tx & 63, w = tx >> 6;
  const int c = lane & 15, g = lane >> 4;

  nlds[tx] = norms[tx];
  nlds[tx + 256] = norms[tx + 256];
  if (tx < 2) lflag[tx] = 0u;

  // ---- stage x: fp32 -> f16 swizzled LDS (paired-d b32 writes, conflict-free)
  float xsum = 0.f;
  {
    const int f4 = tx & 15;     // t-quad
    const int dd = tx >> 4;     // d-pair id 0..15 within 32-d group
    const float* xb = x + (size_t)b * (D_DIM * T_DIM) + t0 + f4 * 4;
    unsigned* xl32 = (unsigned*)xlds;
    #pragma unroll
    for (int p = 0; p < 8; ++p) {
      int d0 = p * 32 + dd * 2;
      float4 va = *(const float4*)(xb + (size_t)d0 * T_DIM);
      float4 vb = *(const float4*)(xb + (size_t)(d0 + 1) * T_DIM);
      int chunk = d0 >> 3;
      float aa[4] = {va.x, va.y, va.z, va.w};
      float bbv[4] = {vb.x, vb.y, vb.z, vb.w};
      #pragma unroll
      for (int j = 0; j < 4; ++j) {
        int row = f4 * 4 + j;
        int slot = (chunk & 24) | ((chunk ^ row) & 7);
        unsigned u = (unsigned)__half_as_ushort(__float2half(aa[j])) |
                     ((unsigned)__half_as_ushort(__float2half(bbv[j])) << 16);
        xl32[row * 128 + slot * 4 + ((d0 & 7) >> 1)] = u;
        xsum = fmaf(aa[j], aa[j], xsum);
        xsum = fmaf(bbv[j], bbv[j], xsum);
      }
    }
  }
  __syncthreads();  // the only staging barrier

  // ---- per-row running (min, min2, argmin); slots si = mi*4+q, row = mi*16+g*4+q
  float tm[16], tm2[16];
  int tidx[16];
  #pragma unroll
  for (int si = 0; si < 16; ++si) { tm[si] = 3.4e38f; tm2[si] = 3.4e38f; tidx[si] = 0; }

  for (int cq = 0; cq < 4; ++cq) {
    const int cb = cq * 128 + w * 32;   // wave's 32 codes this chunk
    f32x4 acc[4][2];
    #pragma unroll
    for (int mi = 0; mi < 4; ++mi) { acc[mi][0] = (f32x4){0,0,0,0}; acc[mi][1] = (f32x4){0,0,0,0}; }

    #pragma unroll
    for (int ch = 0; ch < 8; ++ch) {
      f16x8 bf[2];
      if (USE_WS) {
        #pragma unroll
        for (int nj = 0; nj < 2; ++nj)
          bf[nj] = *(const f16x8*)(e16 + (size_t)(cb + nj * 16 + c) * D_DIM + ch * 32 + g * 8);
      } else {
        #pragma unroll
        for (int nj = 0; nj < 2; ++nj) {
          const float* ep = e + (size_t)(cb + nj * 16 + c) * D_DIM + ch * 32 + g * 8;
          float4 u0 = *(const float4*)ep;
          float4 u1 = *(const float4*)(ep + 4);
          f16x8 r;
          r[0] = (_Float16)(512.f * u0.x); r[1] = (_Float16)(512.f * u0.y);
          r[2] = (_Float16)(512.f * u0.z); r[3] = (_Float16)(512.f * u0.w);
          r[4] = (_Float16)(512.f * u1.x); r[5] = (_Float16)(512.f * u1.y);
          r[6] = (_Float16)(512.f * u1.z); r[7] = (_Float16)(512.f * u1.w);
          bf[nj] = r;
        }
      }
      #pragma unroll
      for (int mi = 0; mi < 4; ++mi) {
        int row = mi * 16 + c;
        int chunk = ch * 4 + g;
        int slot = (chunk & 24) | ((chunk ^ row) & 7);
        f16x8 af = *(const f16x8*)&xlds[row * 256 + slot * 8];
        acc[mi][0] = __builtin_amdgcn_mfma_f32_16x16x32_f16(af, bf[0], acc[mi][0], 0, 0, 0);
        acc[mi][1] = __builtin_amdgcn_mfma_f32_16x16x32_f16(af, bf[1], acc[mi][1], 0, 0, 0);
      }
    }

    // fold: sv = nrm - 2*(m'/512) = fmaf(-1/256, m', nrm)
    float nrm0 = nlds[cb + c], nrm1 = nlds[cb + 16 + c];
    #pragma unroll
    for (int mi = 0; mi < 4; ++mi)
      #pragma unroll
      for (int q = 0; q < 4; ++q) {
        int si = mi * 4 + q;
        float s0 = fmaf(-0.00390625f, acc[mi][0][q], nrm0);
        if (s0 < tm[si]) { tm2[si] = tm[si]; tm[si] = s0; tidx[si] = cb + c; }
        else if (s0 < tm2[si]) tm2[si] = s0;
        float s1 = fmaf(-0.00390625f, acc[mi][1][q], nrm1);
        if (s1 < tm[si]) { tm2[si] = tm[si]; tm[si] = s1; tidx[si] = cb + 16 + c; }
        else if (s1 < tm2[si]) tm2[si] = s1;
      }
  }

  // ---- cross-lane (16 codes per group) reduce with min2
  #pragma unroll
  for (int mi = 0; mi < 4; ++mi)
    #pragma unroll
    for (int q = 0; q < 4; ++q) {
      int si = mi * 4 + q;
      float m = tm[si], m2 = tm2[si];
      int id = tidx[si];
      #pragma unroll
      for (int off = 1; off < 16; off <<= 1) {
        float om = __shfl_xor(m, off, 64);
        float om2 = __shfl_xor(m2, off, 64);
        int oi = __shfl_xor(id, off, 64);
        float nm2 = fminf(fminf(m2, om2), fmaxf(m, om));
        if (om < m || (om == m && oi < id)) { m = om; id = oi; }
        m2 = nm2;
      }
      if (c == 0) {
        int row = mi * 16 + g * 4 + q;
        wmin[w][row] = m; wm2[w][row] = m2; wid[w][row] = id;
      }
    }
  __syncthreads();

  if (tx < 64) {
    float m = wmin[0][tx], m2 = wm2[0][tx];
    int id = wid[0][tx];
    #pragma unroll
    for (int w2 = 1; w2 < 4; ++w2) {
      float om = wmin[w2][tx], om2 = wm2[w2][tx];
      int oi = wid[w2][tx];
      float nm2 = fminf(fminf(m2, om2), fmaxf(m, om));
      if (om < m || (om == m && oi < id)) { m = om; id = oi; }
      m2 = nm2;
    }
    rmin[tx] = m; widx[tx] = id;
    out_idx[(size_t)blk * 64 + tx] = (float)id;
    if (m2 - m <= FMARGIN) atomicOr(&lflag[tx >> 5], 1u << (tx & 31));
  }
  __syncthreads();
  if (tx < 2) bitmap[blk * 2 + tx] = lflag[tx];

  // ---- fused q-write: wave w writes rows [w*16, w*16+16)
  #pragma unroll 4
  for (int i = 0; i < 16; ++i) {
    int row = w * 16 + i;
    int k = widx[row];
    float4 ev = *(const float4*)(e + (size_t)k * D_DIM + lane * 4);
    *(float4*)(out_q + ((size_t)blk * 64 + row) * D_DIM + lane * 4) = ev;
  }

  // ---- loss partial: sum(x^2) + sum(row min scores)
  double dv = (double)xsum + ((tx < 64) ? (double)rmin[tx] : 0.0);
  #pragma unroll
  for (int o = 32; o > 0; o >>= 1) dv += __shfl_down(dv, o, 64);
  if (lane == 0) dred[w] = dv;
  __syncthreads();
  if (tx == 0) bsums[blk] = (dred[0] + dred[1]) + (dred[2] + dred[3]);
}

// Exact fp32 rescan (numpy-replica, validated rounds 2-5) for flagged rows.
__global__ __launch_bounds__(256) void vq_fixup(
    const float* __restrict__ x, const float* __restrict__ e,
    const float* __restrict__ norms, const unsigned* __restrict__ bitmap,
    float* __restrict__ out_q, float* __restrict__ out_idx) {
  __shared__ float xrow[16][257];
  __shared__ float elds[64][257];
  __shared__ float xxr[16];
  __shared__ int list[256];
  __shared__ int lcount;
  __shared__ float redm[16][16];
  __shared__ int   redi[16][16];
  __shared__ int   wk[16];

  const int bidx = blockIdx.x, tx = threadIdx.x;
  if (tx == 0) {
    int cnt = 0;
    for (int wi = 0; wi < 8; ++wi) {
      unsigned u = bitmap[bidx * 8 + wi];
      while (u) {
        int bit = __ffs(u) - 1;
        list[cnt++] = bidx * 256 + wi * 32 + bit;
        u &= u - 1;
      }
    }
    lcount = cnt;
  }
  __syncthreads();
  const int nf = lcount;
  const int ri = tx >> 4, dpart = tx & 15;
  const int r = tx & 15, cg = tx >> 4;

  for (int g0 = 0; g0 < nf; g0 += 16) {
    int R = min(16, nf - g0);
    if (ri < R) {
      int n = list[g0 + ri];
      int b2 = n >> 11, t = n & 2047;
      for (int j = 0; j < 16; ++j) {
        int d = dpart * 16 + j;
        xrow[ri][d] = x[((size_t)(b2 * 256 + d)) * 2048 + t];
      }
    }
    __syncthreads();
    if (tx < R) {
      float res[2];
      #pragma unroll
      for (int h = 0; h < 2; ++h) {
        float r8[8];
        #pragma unroll
        for (int j = 0; j < 8; ++j) { float a = xrow[tx][h * 128 + j]; r8[j] = __fmul_rn(a, a); }
        for (int i = 8; i < 128; i += 8)
          #pragma unroll
          for (int j = 0; j < 8; ++j) { float a = xrow[tx][h * 128 + i + j]; r8[j] = __fadd_rn(r8[j], __fmul_rn(a, a)); }
        res[h] = comb8(r8);
      }
      xxr[tx] = __fadd_rn(res[0], res[1]);
    }
    float m = 3.4e38f; int mi_ = 0;
    for (int ch = 0; ch < 8; ++ch) {
      __syncthreads();
      {
        int er = tx >> 2, qd = tx & 3;
        for (int j = 0; j < 16; ++j)
          *(float4*)&elds[er][qd * 64 + j * 4] =
              *(const float4*)(e + (size_t)(ch * 64 + er) * 256 + qd * 64 + j * 4);
      }
      __syncthreads();
      if (r < R) {
        float a0 = 0.f, a1 = 0.f, a2 = 0.f, a3 = 0.f;
        const float* xr_ = &xrow[r][0];
        const float* e0 = &elds[cg * 4 + 0][0];
        const float* e1 = &elds[cg * 4 + 1][0];
        const float* e2 = &elds[cg * 4 + 2][0];
        const float* e3 = &elds[cg * 4 + 3][0];
        for (int d = 0; d < 256; ++d) {
          float xv = xr_[d];
          a0 = __fmaf_rn(xv, e0[d], a0);
          a1 = __fmaf_rn(xv, e1[d], a1);
          a2 = __fmaf_rn(xv, e2[d], a2);
          a3 = __fmaf_rn(xv, e3[d], a3);
        }
        float av[4] = {a0, a1, a2, a3};
        #pragma unroll
        for (int j = 0; j < 4; ++j) {
          int k = ch * 64 + cg * 4 + j;
          float t1 = __fadd_rn(xxr[r], norms[k]);
          float sv = t1 - 2.0f * av[j];
          if (sv < m) { m = sv; mi_ = k; }
        }
      }
    }
    redm[r][cg] = m; redi[r][cg] = mi_;
    __syncthreads();
    if (tx < R) {
      float mm = redm[tx][0]; int ii = redi[tx][0];
      for (int q2 = 1; q2 < 16; ++q2) {
        float s2 = redm[tx][q2]; int s2i = redi[tx][q2];
        if (s2 < mm || (s2 == mm && s2i < ii)) { mm = s2; ii = s2i; }
      }
      int n = list[g0 + tx];
      out_idx[n] = (float)ii;
      wk[tx] = ii;
    }
    __syncthreads();
    if (ri < R) {
      int n = list[g0 + ri];
      int k = wk[ri];
      for (int j = 0; j < 16; ++j) {
        int d = dpart * 16 + j;
        out_q[(size_t)n * 256 + d] = e[(size_t)k * 256 + d];
      }
    }
    __syncthreads();
  }
}

__global__ __launch_bounds__(256) void vq_final(const double* __restrict__ bs,
                                                float* __restrict__ out_loss) {
  __shared__ double sred[4];
  int t = threadIdx.x;
  double s = 0.0;
  for (int i = t; i < 2048; i += 256) s += bs[i];
  #pragma unroll
  for (int o = 32; o > 0; o >>= 1) s += __shfl_down(s, o, 64);
  if ((t & 63) == 0) sred[t >> 6] = s;
  __syncthreads();
  if (t == 0)
    out_loss[0] = (float)(0.25 * (((sred[0] + sred[1]) + (sred[2] + sred[3])) / (double)Q_ELEMS));
}

extern "C" void kernel_launch(void* const* d_in, const int* in_sizes, int n_in,
                              void* d_out, int out_size, void* d_ws, size_t ws_size,
                              hipStream_t stream) {
  const float* x = (const float*)d_in[0];
  const float* e = (const float*)d_in[1];
  float* out = (float*)d_out;
  float* out_q = out;
  float* out_loss = out + Q_ELEMS;
  float* out_idx = out + Q_ELEMS + 1;

  char* ws = (char*)d_ws;
  float* norms = (float*)ws;
  double* bsums = (double*)(ws + 2048);
  unsigned* bitmap = (unsigned*)(ws + 20480);
  unsigned short* e16 = (unsigned short*)(ws + 36864);
  int use_ws = (ws_size >= 299008) ? 1 : 0;

  vq_prep<<<K_CODES, 256, 0, stream>>>(e, norms, e16, bitmap, use_ws);
  if (use_ws)
    vq_main<1><<<N_ROWS / 64, 256, 0, stream>>>(x, e, norms, e16, out_q, out_idx, bsums, bitmap);
  else
    vq_main<0><<<N_ROWS / 64, 256, 0, stream>>>(x, e, norms, e16, out_q, out_idx, bsums, bitmap);
  vq_fixup<<<512, 256, 0, stream>>>(x, e, norms, bitmap, out_q, out_idx);
  vq_final<<<1, 256, 0, stream>>>(bsums, out_loss);
}

// Round 7
// 413.695 us; speedup vs baseline: 1.2472x; 1.2472x over previous
//
#include <hip/hip_runtime.h>
#include <hip/hip_fp16.h>

#define T_DIM 2048
#define D_DIM 256
#define K_CODES 512
#define N_ROWS 131072
#define Q_ELEMS 33554432
#define FMARGIN 2.0e-4f

typedef __attribute__((ext_vector_type(8))) _Float16 f16x8;
typedef __attribute__((ext_vector_type(4))) float f32x4;

// ws layout (bytes):
// [0, 2048)        norms (512 f32, numpy-pairwise-exact)
// [2048, 18432)    bsums (2048 f64)
// [20480, 36864)   bitmap (4096 u32; bit = row needs FULL exact rescan, rare)
// [36864, 299008)  e16: f16(512*e) [512][256]  (only if ws fits)

__device__ __forceinline__ float comb8(const float* r) {
  return ((r[0] + r[1]) + (r[2] + r[3])) + ((r[4] + r[5]) + (r[6] + r[7]));
}

// top-3 merge: (m,id,m2,id2,m3) <- merge with (om,oi,om2,oi2,om3); ties -> lower id
__device__ __forceinline__ void merge3(float& m, int& id, float& m2, int& id2, float& m3,
                                       float om, int oi, float om2, int oi2, float om3) {
  if (om < m || (om == m && oi < id)) {
    float tm = m; int ti = id; float tm2 = m2;
    m = om; id = oi;
    if (om2 < tm || (om2 == tm && oi2 < ti)) { m2 = om2; id2 = oi2; m3 = fminf(tm, om3); }
    else { m2 = tm; id2 = ti; m3 = fminf(tm2, om2); }
  } else {
    if (om < m2 || (om == m2 && oi < id2)) { float tm2 = m2; m2 = om; id2 = oi; m3 = fminf(tm2, om2); }
    else { m3 = fminf(m3, om); }
  }
}

__global__ __launch_bounds__(256) void vq_prep(const float* __restrict__ e,
                                               float* __restrict__ norms,
                                               unsigned short* __restrict__ e16,
                                               unsigned* __restrict__ bitmap,
                                               int use_ws) {
  __shared__ float srow[D_DIM];
  int k = blockIdx.x, t = threadIdx.x;
  float v = e[k * D_DIM + t];
  srow[t] = v;
  if (use_ws) e16[k * D_DIM + t] = __half_as_ushort(__float2half(512.0f * v));
  if (t < 8) bitmap[k * 8 + t] = 0u;
  __syncthreads();
  if (t == 0) {
    float res[2];
    #pragma unroll
    for (int h = 0; h < 2; ++h) {
      float r[8];
      #pragma unroll
      for (int j = 0; j < 8; ++j) { float a = srow[h * 128 + j]; r[j] = __fmul_rn(a, a); }
      for (int i = 8; i < 128; i += 8)
        #pragma unroll
        for (int j = 0; j < 8; ++j) { float a = srow[h * 128 + i + j]; r[j] = __fadd_rn(r[j], __fmul_rn(a, a)); }
      res[h] = comb8(r);
    }
    norms[k] = __fadd_rn(res[0], res[1]);
  }
}

template <int USE_WS>
__global__ __launch_bounds__(256, 4) void vq_main(
    const float* __restrict__ x, const float* __restrict__ e,
    const float* __restrict__ norms, const unsigned short* __restrict__ e16,
    float* __restrict__ out_q, float* __restrict__ out_idx,
    double* __restrict__ bsums, unsigned* __restrict__ bitmap) {
  __shared__ unsigned short xlds[64 * 256];   // 32 KB f16, chunk-swizzled
  __shared__ float nlds[K_CODES];
  __shared__ float wredm[2][64], wredm2[2][64], wredm3[2][64];
  __shared__ int   wredi[2][64], wredi2[2][64];
  __shared__ float rmin[64];
  __shared__ int   widx[64];
  __shared__ float xrow[256];
  __shared__ float xr16[16];
  __shared__ double dred[4];

  const int tx = threadIdx.x;
  const int blk = blockIdx.x;                 // 2048
  const int b = blk >> 5, t0 = (blk & 31) * 64;
  const int lane = tx & 63, w = tx >> 6;
  const int wm = w & 1, wn = w >> 1;          // rows wm*32..+32, code-half wn
  const int c = lane & 15, g = lane >> 4;

  nlds[tx] = norms[tx];
  nlds[tx + 256] = norms[tx + 256];

  // ---- stage x: fp32 -> f16 swizzled LDS (paired-d b32, ~2-way banks)
  float xsum = 0.f;
  {
    const int f4 = tx >> 4;       // t-quad 0..15
    const int dd = tx & 15;       // d-pair 0..15 within 32-d group
    const float* xb = x + (size_t)b * (D_DIM * T_DIM) + t0 + f4 * 4;
    unsigned* xl32 = (unsigned*)xlds;
    #pragma unroll
    for (int p = 0; p < 8; ++p) {
      int d0 = p * 32 + dd * 2;
      float4 va = *(const float4*)(xb + (size_t)d0 * T_DIM);
      float4 vb = *(const float4*)(xb + (size_t)(d0 + 1) * T_DIM);
      int chunk = d0 >> 3;
      float aa[4] = {va.x, va.y, va.z, va.w};
      float bbv[4] = {vb.x, vb.y, vb.z, vb.w};
      #pragma unroll
      for (int j = 0; j < 4; ++j) {
        int row = f4 * 4 + j;
        int slot = (chunk & 24) | ((chunk ^ row) & 7);
        unsigned u = (unsigned)__half_as_ushort(__float2half(aa[j])) |
                     ((unsigned)__half_as_ushort(__float2half(bbv[j])) << 16);
        xl32[row * 128 + slot * 4 + ((d0 & 7) >> 1)] = u;
        xsum = fmaf(aa[j], aa[j], xsum);
        xsum = fmaf(bbv[j], bbv[j], xsum);
      }
    }
  }
  __syncthreads();

  // ---- per-slot running top-3; slot si = mi*4+q -> row wm*32+mi*16+g*4+q
  float m[8], m2[8], m3[8];
  int id[8], id2[8];
  #pragma unroll
  for (int si = 0; si < 8; ++si) { m[si] = 3.4e38f; m2[si] = 3.4e38f; m3[si] = 3.4e38f; id[si] = 0; id2[si] = 0; }

  for (int cq = 0; cq < 8; ++cq) {            // 64 codes per cq
    const int cb = cq * 64 + wn * 32;
    f32x4 acc[2][2];
    #pragma unroll
    for (int mi = 0; mi < 2; ++mi) { acc[mi][0] = (f32x4){0,0,0,0}; acc[mi][1] = (f32x4){0,0,0,0}; }

    #pragma unroll
    for (int ch = 0; ch < 8; ++ch) {
      f16x8 bf[2];
      if (USE_WS) {
        bf[0] = *(const f16x8*)(e16 + (size_t)(cb + c) * D_DIM + ch * 32 + g * 8);
        bf[1] = *(const f16x8*)(e16 + (size_t)(cb + 16 + c) * D_DIM + ch * 32 + g * 8);
      } else {
        #pragma unroll
        for (int nj = 0; nj < 2; ++nj) {
          const float* ep = e + (size_t)(cb + nj * 16 + c) * D_DIM + ch * 32 + g * 8;
          float4 u0 = *(const float4*)ep;
          float4 u1 = *(const float4*)(ep + 4);
          f16x8 r;
          r[0] = (_Float16)(512.f * u0.x); r[1] = (_Float16)(512.f * u0.y);
          r[2] = (_Float16)(512.f * u0.z); r[3] = (_Float16)(512.f * u0.w);
          r[4] = (_Float16)(512.f * u1.x); r[5] = (_Float16)(512.f * u1.y);
          r[6] = (_Float16)(512.f * u1.z); r[7] = (_Float16)(512.f * u1.w);
          bf[nj] = r;
        }
      }
      #pragma unroll
      for (int mi = 0; mi < 2; ++mi) {
        int row = wm * 32 + mi * 16 + c;
        int chunk = ch * 4 + g;
        int slot = (chunk & 24) | ((chunk ^ row) & 7);
        f16x8 af = *(const f16x8*)&xlds[row * 256 + slot * 8];
        acc[mi][0] = __builtin_amdgcn_mfma_f32_16x16x32_f16(af, bf[0], acc[mi][0], 0, 0, 0);
        acc[mi][1] = __builtin_amdgcn_mfma_f32_16x16x32_f16(af, bf[1], acc[mi][1], 0, 0, 0);
      }
    }
    // fold (codes ascending: nj 0 then 1)
    #pragma unroll
    for (int nj = 0; nj < 2; ++nj) {
      float nrm = nlds[cb + nj * 16 + c];
      int code = cb + nj * 16 + c;
      #pragma unroll
      for (int mi = 0; mi < 2; ++mi)
        #pragma unroll
        for (int q = 0; q < 4; ++q) {
          int si = mi * 4 + q;
          float sv = fmaf(-0.00390625f, acc[mi][nj][q], nrm);  // nrm - 2*dot
          if (sv < m[si])       { m3[si] = m2[si]; m2[si] = m[si]; id2[si] = id[si]; m[si] = sv; id[si] = code; }
          else if (sv < m2[si]) { m3[si] = m2[si]; m2[si] = sv; id2[si] = code; }
          else if (sv < m3[si]) { m3[si] = sv; }
        }
    }
  }

  // ---- cross-lane (16 codes over c) top-3 butterfly
  #pragma unroll
  for (int si = 0; si < 8; ++si) {
    float M = m[si], M2 = m2[si], M3 = m3[si];
    int I = id[si], I2 = id2[si];
    #pragma unroll
    for (int off = 1; off < 16; off <<= 1) {
      float om = __shfl_xor(M, off, 64), om2 = __shfl_xor(M2, off, 64), om3 = __shfl_xor(M3, off, 64);
      int oi = __shfl_xor(I, off, 64), oi2 = __shfl_xor(I2, off, 64);
      merge3(M, I, M2, I2, M3, om, oi, om2, oi2, om3);
    }
    if (c == 0) {
      int row = wm * 32 + (si >> 2) * 16 + g * 4 + (si & 3);
      wredm[wn][row] = M; wredm2[wn][row] = M2; wredm3[wn][row] = M3;
      wredi[wn][row] = I; wredi2[wn][row] = I2;
    }
  }
  __syncthreads();

  // ---- wave 0: merge code-halves, flag, inline exact pair-resolution
  if (tx < 64) {
    float M = wredm[0][tx], M2 = wredm2[0][tx], M3 = wredm3[0][tx];
    int I = wredi[0][tx], I2 = wredi2[0][tx];
    merge3(M, I, M2, I2, M3, wredm[1][tx], wredi[1][tx], wredm2[1][tx], wredi2[1][tx], wredm3[1][tx]);
    rmin[tx] = M;
    widx[tx] = I;
    bool rescan = (M3 - M <= FMARGIN);                 // >=3 candidates: full rescan
    bool pairf  = (M2 - M <= FMARGIN) && !rescan;      // exactly-2: inline resolve
    unsigned long long bm3 = __ballot(rescan);
    if (lane == 0) {
      bitmap[blk * 2] = (unsigned)bm3;
      bitmap[blk * 2 + 1] = (unsigned)(bm3 >> 32);
    }
    unsigned long long bm = __ballot(pairf);
    while (bm) {
      int row = __ffsll(bm) - 1; bm &= bm - 1;
      int k1 = __shfl(I, row), k2 = __shfl(I2, row);
      int ka = min(k1, k2), kb = max(k1, k2);
      int trow = t0 + row;
      #pragma unroll
      for (int j = 0; j < 4; ++j)
        xrow[lane + 64 * j] = x[((size_t)(b * 256 + lane + 64 * j)) * 2048 + trow];
      asm volatile("s_waitcnt vmcnt(0) lgkmcnt(0)" ::: "memory");
      if (lane < 16) {  // exact numpy-pairwise ||x||^2: 16 chains
        int h = lane >> 3, jj = lane & 7;
        float a0 = xrow[h * 128 + jj];
        float r = __fmul_rn(a0, a0);
        for (int i = 1; i < 16; ++i) {
          float a = xrow[h * 128 + i * 8 + jj];
          r = __fadd_rn(r, __fmul_rn(a, a));
        }
        xr16[lane] = r;
      }
      asm volatile("s_waitcnt lgkmcnt(0)" ::: "memory");
      float sv = 0.f;
      if (lane < 2) {
        int k = lane ? kb : ka;
        float a = 0.f;
        const float* ep = e + (size_t)k * D_DIM;
        #pragma unroll 4
        for (int d = 0; d < 256; ++d) a = __fmaf_rn(xrow[d], ep[d], a);
        float xx = __fadd_rn(comb8(&xr16[0]), comb8(&xr16[8]));
        float t1 = __fadd_rn(xx, nlds[k]);
        sv = t1 - 2.0f * a;
      }
      float s0 = __shfl(sv, 0), s1 = __shfl(sv, 1);
      if (lane == 0) widx[row] = (s1 < s0) ? kb : ka;   // tie -> ka (lower)
    }
  }
  __syncthreads();

  // ---- writes: idx + fused q-gather (final widx)
  if (tx < 64) out_idx[(size_t)blk * 64 + tx] = (float)widx[tx];
  #pragma unroll 4
  for (int i = 0; i < 16; ++i) {
    int row = w * 16 + i;
    int k = widx[row];
    float4 ev = *(const float4*)(e + (size_t)k * D_DIM + lane * 4);
    *(float4*)(out_q + ((size_t)blk * 64 + row) * D_DIM + lane * 4) = ev;
  }

  // ---- loss partial: sum(x^2) + sum(row min scores)
  double dv = (double)xsum + ((tx < 64) ? (double)rmin[tx] : 0.0);
  #pragma unroll
  for (int o = 32; o > 0; o >>= 1) dv += __shfl_down(dv, o, 64);
  if (lane == 0) dred[w] = dv;
  __syncthreads();
  if (tx == 0) bsums[blk] = (dred[0] + dred[1]) + (dred[2] + dred[3]);
}

// Full exact rescan (wave-per-row, lane-parallel codes) for rare >=3-way rows.
__global__ __launch_bounds__(64) void vq_fixup(
    const float* __restrict__ x, const float* __restrict__ e,
    const float* __restrict__ norms, const unsigned* __restrict__ bitmap,
    float* __restrict__ out_q, float* __restrict__ out_idx) {
  __shared__ float xrow[256];
  __shared__ float xr16[16];
  const int blk = blockIdx.x, lane = threadIdx.x;
  unsigned long long bm = (unsigned long long)bitmap[blk * 2] |
                          ((unsigned long long)bitmap[blk * 2 + 1] << 32);
  if (!bm) return;
  const int b = blk >> 5, t0 = (blk & 31) * 64;
  while (bm) {
    int row = __ffsll(bm) - 1; bm &= bm - 1;
    int trow = t0 + row;
    #pragma unroll
    for (int j = 0; j < 4; ++j)
      xrow[lane + 64 * j] = x[((size_t)(b * 256 + lane + 64 * j)) * 2048 + trow];
    asm volatile("s_waitcnt vmcnt(0) lgkmcnt(0)" ::: "memory");
    if (lane < 16) {
      int h = lane >> 3, jj = lane & 7;
      float a0 = xrow[h * 128 + jj];
      float r = __fmul_rn(a0, a0);
      for (int i = 1; i < 16; ++i) {
        float a = xrow[h * 128 + i * 8 + jj];
        r = __fadd_rn(r, __fmul_rn(a, a));
      }
      xr16[lane] = r;
    }
    asm volatile("s_waitcnt lgkmcnt(0)" ::: "memory");
    float xx = __fadd_rn(comb8(&xr16[0]), comb8(&xr16[8]));
    // 8 exact chains: codes lane*8 .. lane*8+7 (ascending)
    float am[8];
    #pragma unroll
    for (int cc = 0; cc < 8; ++cc) am[cc] = 0.f;
    const float* eb = e + (size_t)(lane * 8) * D_DIM;
    for (int d4 = 0; d4 < 64; ++d4) {
      float4 xv = *(const float4*)&xrow[d4 * 4];
      #pragma unroll
      for (int cc = 0; cc < 8; ++cc) {
        float4 ev = *(const float4*)(eb + (size_t)cc * D_DIM + d4 * 4);
        am[cc] = __fmaf_rn(xv.x, ev.x, am[cc]);
        am[cc] = __fmaf_rn(xv.y, ev.y, am[cc]);
        am[cc] = __fmaf_rn(xv.z, ev.z, am[cc]);
        am[cc] = __fmaf_rn(xv.w, ev.w, am[cc]);
      }
    }
    float lm = 3.4e38f; int lk = 0;
    #pragma unroll
    for (int cc = 0; cc < 8; ++cc) {
      int k = lane * 8 + cc;
      float t1 = __fadd_rn(xx, norms[k]);
      float sv = t1 - 2.0f * am[cc];
      if (sv < lm) { lm = sv; lk = k; }    // ascending -> first-min
    }
    #pragma unroll
    for (int off = 1; off < 64; off <<= 1) {
      float om = __shfl_xor(lm, off, 64);
      int oi = __shfl_xor(lk, off, 64);
      if (om < lm || (om == lm && oi < lk)) { lm = om; lk = oi; }
    }
    if (lane == 0) out_idx[(size_t)blk * 64 + row] = (float)lk;
    int wk = __shfl(lk, 0);
    float4 ev = *(const float4*)(e + (size_t)wk * D_DIM + lane * 4);
    *(float4*)(out_q + ((size_t)blk * 64 + row) * D_DIM + lane * 4) = ev;
  }
}

__global__ __launch_bounds__(256) void vq_final(const double* __restrict__ bs,
                                                float* __restrict__ out_loss) {
  __shared__ double sred[4];
  int t = threadIdx.x;
  double s = 0.0;
  for (int i = t; i < 2048; i += 256) s += bs[i];
  #pragma unroll
  for (int o = 32; o > 0; o >>= 1) s += __shfl_down(s, o, 64);
  if ((t & 63) == 0) sred[t >> 6] = s;
  __syncthreads();
  if (t == 0)
    out_loss[0] = (float)(0.25 * (((sred[0] + sred[1]) + (sred[2] + sred[3])) / (double)Q_ELEMS));
}

extern "C" void kernel_launch(void* const* d_in, const int* in_sizes, int n_in,
                              void* d_out, int out_size, void* d_ws, size_t ws_size,
                              hipStream_t stream) {
  const float* x = (const float*)d_in[0];
  const float* e = (const float*)d_in[1];
  float* out = (float*)d_out;
  float* out_q = out;
  float* out_loss = out + Q_ELEMS;
  float* out_idx = out + Q_ELEMS + 1;

  char* ws = (char*)d_ws;
  float* norms = (float*)ws;
  double* bsums = (double*)(ws + 2048);
  unsigned* bitmap = (unsigned*)(ws + 20480);
  unsigned short* e16 = (unsigned short*)(ws + 36864);
  int use_ws = (ws_size >= 299008) ? 1 : 0;

  vq_prep<<<K_CODES, 256, 0, stream>>>(e, norms, e16, bitmap, use_ws);
  if (use_ws)
    vq_main<1><<<N_ROWS / 64, 256, 0, stream>>>(x, e, norms, e16, out_q, out_idx, bsums, bitmap);
  else
    vq_main<0><<<N_ROWS / 64, 256, 0, stream>>>(x, e, norms, e16, out_q, out_idx, bsums, bitmap);
  vq_fixup<<<N_ROWS / 64, 64, 0, stream>>>(x, e, norms, bitmap, out_q, out_idx);
  vq_final<<<1, 256, 0, stream>>>(bsums, out_loss);
}

// Round 8
// 404.802 us; speedup vs baseline: 1.2746x; 1.0220x over previous
//
#include <hip/hip_runtime.h>
#include <hip/hip_fp16.h>

#define T_DIM 2048
#define D_DIM 256
#define K_CODES 512
#define N_ROWS 131072
#define Q_ELEMS 33554432
#define FMARGIN 2.0e-4f

typedef __attribute__((ext_vector_type(8))) _Float16 f16x8;
typedef __attribute__((ext_vector_type(4))) float f32x4;

// ws layout (bytes):
// [0, 2048)        norms (512 f32, numpy-pairwise-exact)
// [2048, 18432)    bsums (2048 f64)
// [20480, 36864)   bitmap (4096 u32; bit = row needs FULL exact rescan, rare)
// [36864, 299008)  e16: f16(512*e) [512][256]  (only if ws fits)

__device__ __forceinline__ float comb8(const float* r) {
  return ((r[0] + r[1]) + (r[2] + r[3])) + ((r[4] + r[5]) + (r[6] + r[7]));
}

// top-3 merge: (m,id,m2,id2,m3) <- merge with (om,oi,om2,oi2,om3); ties -> lower id
__device__ __forceinline__ void merge3(float& m, int& id, float& m2, int& id2, float& m3,
                                       float om, int oi, float om2, int oi2, float om3) {
  if (om < m || (om == m && oi < id)) {
    float tm = m; int ti = id; float tm2 = m2;
    m = om; id = oi;
    if (om2 < tm || (om2 == tm && oi2 < ti)) { m2 = om2; id2 = oi2; m3 = fminf(tm, om3); }
    else { m2 = tm; id2 = ti; m3 = fminf(tm2, om2); }
  } else {
    if (om < m2 || (om == m2 && oi < id2)) { float tm2 = m2; m2 = om; id2 = oi; m3 = fminf(tm2, om2); }
    else { m3 = fminf(m3, om); }
  }
}

__global__ __launch_bounds__(256) void vq_prep(const float* __restrict__ e,
                                               float* __restrict__ norms,
                                               unsigned short* __restrict__ e16,
                                               unsigned* __restrict__ bitmap,
                                               int use_ws) {
  __shared__ float srow[D_DIM];
  int k = blockIdx.x, t = threadIdx.x;
  float v = e[k * D_DIM + t];
  srow[t] = v;
  if (use_ws) e16[k * D_DIM + t] = __half_as_ushort(__float2half(512.0f * v));
  if (t < 8) bitmap[k * 8 + t] = 0u;
  __syncthreads();
  if (t == 0) {
    float res[2];
    #pragma unroll
    for (int h = 0; h < 2; ++h) {
      float r[8];
      #pragma unroll
      for (int j = 0; j < 8; ++j) { float a = srow[h * 128 + j]; r[j] = __fmul_rn(a, a); }
      for (int i = 8; i < 128; i += 8)
        #pragma unroll
        for (int j = 0; j < 8; ++j) { float a = srow[h * 128 + i + j]; r[j] = __fadd_rn(r[j], __fmul_rn(a, a)); }
      res[h] = comb8(r);
    }
    norms[k] = __fadd_rn(res[0], res[1]);
  }
}

// NOTE: hipcc treats the 2nd launch_bounds arg CUDA-style (min blocks/CU over a
// 65536-reg model): (256,4) capped VGPR at 64 -> 200 MB spill traffic (round 7).
// (256,2) -> cap 128, fits our ~110 live regs, still allows 4 waves/SIMD.
template <int USE_WS>
__global__ __launch_bounds__(256, 2) void vq_main(
    const float* __restrict__ x, const float* __restrict__ e,
    const float* __restrict__ norms, const unsigned short* __restrict__ e16,
    float* __restrict__ out_q, float* __restrict__ out_idx,
    double* __restrict__ bsums, unsigned* __restrict__ bitmap) {
  __shared__ unsigned short xlds[64 * 256];   // 32 KB f16, chunk-swizzled
  __shared__ float nlds[K_CODES];
  __shared__ float wredm[2][64], wredm2[2][64], wredm3[2][64];
  __shared__ int   wredi[2][64], wredi2[2][64];
  __shared__ float rmin[64];
  __shared__ int   widx[64];
  __shared__ float xrow[256];
  __shared__ float xr16[16];
  __shared__ double dred[4];

  const int tx = threadIdx.x;
  const int blk = blockIdx.x;                 // 2048
  const int b = blk >> 5, t0 = (blk & 31) * 64;
  const int lane = tx & 63, w = tx >> 6;
  const int wm = w & 1, wn = w >> 1;          // rows wm*32..+32, code-half wn
  const int c = lane & 15, g = lane >> 4;

  nlds[tx] = norms[tx];
  nlds[tx + 256] = norms[tx + 256];

  // ---- stage x: fp32 -> f16 swizzled LDS (paired-d b32, ~2-way banks)
  float xsum = 0.f;
  {
    const int f4 = tx >> 4;       // t-quad 0..15
    const int dd = tx & 15;       // d-pair 0..15 within 32-d group
    const float* xb = x + (size_t)b * (D_DIM * T_DIM) + t0 + f4 * 4;
    unsigned* xl32 = (unsigned*)xlds;
    #pragma unroll
    for (int p = 0; p < 8; ++p) {
      int d0 = p * 32 + dd * 2;
      float4 va = *(const float4*)(xb + (size_t)d0 * T_DIM);
      float4 vb = *(const float4*)(xb + (size_t)(d0 + 1) * T_DIM);
      int chunk = d0 >> 3;
      float aa[4] = {va.x, va.y, va.z, va.w};
      float bbv[4] = {vb.x, vb.y, vb.z, vb.w};
      #pragma unroll
      for (int j = 0; j < 4; ++j) {
        int row = f4 * 4 + j;
        int slot = (chunk & 24) | ((chunk ^ row) & 7);
        unsigned u = (unsigned)__half_as_ushort(__float2half(aa[j])) |
                     ((unsigned)__half_as_ushort(__float2half(bbv[j])) << 16);
        xl32[row * 128 + slot * 4 + ((d0 & 7) >> 1)] = u;
        xsum = fmaf(aa[j], aa[j], xsum);
        xsum = fmaf(bbv[j], bbv[j], xsum);
      }
    }
  }
  __syncthreads();

  // ---- per-slot running top-3; slot si = mi*4+q -> row wm*32+mi*16+g*4+q
  float m[8], m2[8], m3[8];
  int id[8], id2[8];
  #pragma unroll
  for (int si = 0; si < 8; ++si) { m[si] = 3.4e38f; m2[si] = 3.4e38f; m3[si] = 3.4e38f; id[si] = 0; id2[si] = 0; }

  for (int cq = 0; cq < 8; ++cq) {            // 64 codes per cq
    const int cb = cq * 64 + wn * 32;
    f32x4 acc[2][2];
    #pragma unroll
    for (int mi = 0; mi < 2; ++mi) { acc[mi][0] = (f32x4){0,0,0,0}; acc[mi][1] = (f32x4){0,0,0,0}; }

    #pragma unroll
    for (int ch = 0; ch < 8; ++ch) {
      f16x8 bf[2];
      if (USE_WS) {
        bf[0] = *(const f16x8*)(e16 + (size_t)(cb + c) * D_DIM + ch * 32 + g * 8);
        bf[1] = *(const f16x8*)(e16 + (size_t)(cb + 16 + c) * D_DIM + ch * 32 + g * 8);
      } else {
        #pragma unroll
        for (int nj = 0; nj < 2; ++nj) {
          const float* ep = e + (size_t)(cb + nj * 16 + c) * D_DIM + ch * 32 + g * 8;
          float4 u0 = *(const float4*)ep;
          float4 u1 = *(const float4*)(ep + 4);
          f16x8 r;
          r[0] = (_Float16)(512.f * u0.x); r[1] = (_Float16)(512.f * u0.y);
          r[2] = (_Float16)(512.f * u0.z); r[3] = (_Float16)(512.f * u0.w);
          r[4] = (_Float16)(512.f * u1.x); r[5] = (_Float16)(512.f * u1.y);
          r[6] = (_Float16)(512.f * u1.z); r[7] = (_Float16)(512.f * u1.w);
          bf[nj] = r;
        }
      }
      #pragma unroll
      for (int mi = 0; mi < 2; ++mi) {
        int row = wm * 32 + mi * 16 + c;
        int chunk = ch * 4 + g;
        int slot = (chunk & 24) | ((chunk ^ row) & 7);
        f16x8 af = *(const f16x8*)&xlds[row * 256 + slot * 8];
        acc[mi][0] = __builtin_amdgcn_mfma_f32_16x16x32_f16(af, bf[0], acc[mi][0], 0, 0, 0);
        acc[mi][1] = __builtin_amdgcn_mfma_f32_16x16x32_f16(af, bf[1], acc[mi][1], 0, 0, 0);
      }
    }
    // fold (codes ascending: nj 0 then 1)
    #pragma unroll
    for (int nj = 0; nj < 2; ++nj) {
      float nrm = nlds[cb + nj * 16 + c];
      int code = cb + nj * 16 + c;
      #pragma unroll
      for (int mi = 0; mi < 2; ++mi)
        #pragma unroll
        for (int q = 0; q < 4; ++q) {
          int si = mi * 4 + q;
          float sv = fmaf(-0.00390625f, acc[mi][nj][q], nrm);  // nrm - 2*dot
          if (sv < m[si])       { m3[si] = m2[si]; m2[si] = m[si]; id2[si] = id[si]; m[si] = sv; id[si] = code; }
          else if (sv < m2[si]) { m3[si] = m2[si]; m2[si] = sv; id2[si] = code; }
          else if (sv < m3[si]) { m3[si] = sv; }
        }
    }
  }

  // ---- cross-lane (16 codes over c) top-3 butterfly
  #pragma unroll
  for (int si = 0; si < 8; ++si) {
    float M = m[si], M2 = m2[si], M3 = m3[si];
    int I = id[si], I2 = id2[si];
    #pragma unroll
    for (int off = 1; off < 16; off <<= 1) {
      float om = __shfl_xor(M, off, 64), om2 = __shfl_xor(M2, off, 64), om3 = __shfl_xor(M3, off, 64);
      int oi = __shfl_xor(I, off, 64), oi2 = __shfl_xor(I2, off, 64);
      merge3(M, I, M2, I2, M3, om, oi, om2, oi2, om3);
    }
    if (c == 0) {
      int row = wm * 32 + (si >> 2) * 16 + g * 4 + (si & 3);
      wredm[wn][row] = M; wredm2[wn][row] = M2; wredm3[wn][row] = M3;
      wredi[wn][row] = I; wredi2[wn][row] = I2;
    }
  }
  __syncthreads();

  // ---- wave 0: merge code-halves, flag, inline exact pair-resolution
  if (tx < 64) {
    float M = wredm[0][tx], M2 = wredm2[0][tx], M3 = wredm3[0][tx];
    int I = wredi[0][tx], I2 = wredi2[0][tx];
    merge3(M, I, M2, I2, M3, wredm[1][tx], wredi[1][tx], wredm2[1][tx], wredi2[1][tx], wredm3[1][tx]);
    rmin[tx] = M;
    widx[tx] = I;
    bool rescan = (M3 - M <= FMARGIN);                 // >=3 candidates: full rescan
    bool pairf  = (M2 - M <= FMARGIN) && !rescan;      // exactly-2: inline resolve
    unsigned long long bm3 = __ballot(rescan);
    if (lane == 0) {
      bitmap[blk * 2] = (unsigned)bm3;
      bitmap[blk * 2 + 1] = (unsigned)(bm3 >> 32);
    }
    unsigned long long bm = __ballot(pairf);
    while (bm) {
      int row = __ffsll(bm) - 1; bm &= bm - 1;
      int k1 = __shfl(I, row), k2 = __shfl(I2, row);
      int ka = min(k1, k2), kb = max(k1, k2);
      int trow = t0 + row;
      #pragma unroll
      for (int j = 0; j < 4; ++j)
        xrow[lane + 64 * j] = x[((size_t)(b * 256 + lane + 64 * j)) * 2048 + trow];
      asm volatile("s_waitcnt vmcnt(0) lgkmcnt(0)" ::: "memory");
      if (lane < 16) {  // exact numpy-pairwise ||x||^2: 16 chains
        int h = lane >> 3, jj = lane & 7;
        float a0 = xrow[h * 128 + jj];
        float r = __fmul_rn(a0, a0);
        for (int i = 1; i < 16; ++i) {
          float a = xrow[h * 128 + i * 8 + jj];
          r = __fadd_rn(r, __fmul_rn(a, a));
        }
        xr16[lane] = r;
      }
      asm volatile("s_waitcnt lgkmcnt(0)" ::: "memory");
      float sv = 0.f;
      if (lane < 2) {
        int k = lane ? kb : ka;
        float a = 0.f;
        const float* ep = e + (size_t)k * D_DIM;
        #pragma unroll 4
        for (int d = 0; d < 256; ++d) a = __fmaf_rn(xrow[d], ep[d], a);
        float xx = __fadd_rn(comb8(&xr16[0]), comb8(&xr16[8]));
        float t1 = __fadd_rn(xx, nlds[k]);
        sv = t1 - 2.0f * a;
      }
      float s0 = __shfl(sv, 0), s1 = __shfl(sv, 1);
      if (lane == 0) widx[row] = (s1 < s0) ? kb : ka;   // tie -> ka (lower)
    }
  }
  __syncthreads();

  // ---- writes: idx + fused q-gather (final widx)
  if (tx < 64) out_idx[(size_t)blk * 64 + tx] = (float)widx[tx];
  #pragma unroll 4
  for (int i = 0; i < 16; ++i) {
    int row = w * 16 + i;
    int k = widx[row];
    float4 ev = *(const float4*)(e + (size_t)k * D_DIM + lane * 4);
    *(float4*)(out_q + ((size_t)blk * 64 + row) * D_DIM + lane * 4) = ev;
  }

  // ---- loss partial: sum(x^2) + sum(row min scores)
  double dv = (double)xsum + ((tx < 64) ? (double)rmin[tx] : 0.0);
  #pragma unroll
  for (int o = 32; o > 0; o >>= 1) dv += __shfl_down(dv, o, 64);
  if (lane == 0) dred[w] = dv;
  __syncthreads();
  if (tx == 0) bsums[blk] = (dred[0] + dred[1]) + (dred[2] + dred[3]);
}

// Full exact rescan (wave-per-row, lane-parallel codes) for rare >=3-way rows.
__global__ __launch_bounds__(64) void vq_fixup(
    const float* __restrict__ x, const float* __restrict__ e,
    const float* __restrict__ norms, const unsigned* __restrict__ bitmap,
    float* __restrict__ out_q, float* __restrict__ out_idx) {
  __shared__ float xrow[256];
  __shared__ float xr16[16];
  const int blk = blockIdx.x, lane = threadIdx.x;
  unsigned long long bm = (unsigned long long)bitmap[blk * 2] |
                          ((unsigned long long)bitmap[blk * 2 + 1] << 32);
  if (!bm) return;
  const int b = blk >> 5, t0 = (blk & 31) * 64;
  while (bm) {
    int row = __ffsll(bm) - 1; bm &= bm - 1;
    int trow = t0 + row;
    #pragma unroll
    for (int j = 0; j < 4; ++j)
      xrow[lane + 64 * j] = x[((size_t)(b * 256 + lane + 64 * j)) * 2048 + trow];
    asm volatile("s_waitcnt vmcnt(0) lgkmcnt(0)" ::: "memory");
    if (lane < 16) {
      int h = lane >> 3, jj = lane & 7;
      float a0 = xrow[h * 128 + jj];
      float r = __fmul_rn(a0, a0);
      for (int i = 1; i < 16; ++i) {
        float a = xrow[h * 128 + i * 8 + jj];
        r = __fadd_rn(r, __fmul_rn(a, a));
      }
      xr16[lane] = r;
    }
    asm volatile("s_waitcnt lgkmcnt(0)" ::: "memory");
    float xx = __fadd_rn(comb8(&xr16[0]), comb8(&xr16[8]));
    // 8 exact chains: codes lane*8 .. lane*8+7 (ascending)
    float am[8];
    #pragma unroll
    for (int cc = 0; cc < 8; ++cc) am[cc] = 0.f;
    const float* eb = e + (size_t)(lane * 8) * D_DIM;
    for (int d4 = 0; d4 < 64; ++d4) {
      float4 xv = *(const float4*)&xrow[d4 * 4];
      #pragma unroll
      for (int cc = 0; cc < 8; ++cc) {
        float4 ev = *(const float4*)(eb + (size_t)cc * D_DIM + d4 * 4);
        am[cc] = __fmaf_rn(xv.x, ev.x, am[cc]);
        am[cc] = __fmaf_rn(xv.y, ev.y, am[cc]);
        am[cc] = __fmaf_rn(xv.z, ev.z, am[cc]);
        am[cc] = __fmaf_rn(xv.w, ev.w, am[cc]);
      }
    }
    float lm = 3.4e38f; int lk = 0;
    #pragma unroll
    for (int cc = 0; cc < 8; ++cc) {
      int k = lane * 8 + cc;
      float t1 = __fadd_rn(xx, norms[k]);
      float sv = t1 - 2.0f * am[cc];
      if (sv < lm) { lm = sv; lk = k; }    // ascending -> first-min
    }
    #pragma unroll
    for (int off = 1; off < 64; off <<= 1) {
      float om = __shfl_xor(lm, off, 64);
      int oi = __shfl_xor(lk, off, 64);
      if (om < lm || (om == lm && oi < lk)) { lm = om; lk = oi; }
    }
    if (lane == 0) out_idx[(size_t)blk * 64 + row] = (float)lk;
    int wk = __shfl(lk, 0);
    float4 ev = *(const float4*)(e + (size_t)wk * D_DIM + lane * 4);
    *(float4*)(out_q + ((size_t)blk * 64 + row) * D_DIM + lane * 4) = ev;
  }
}

__global__ __launch_bounds__(256) void vq_final(const double* __restrict__ bs,
                                                float* __restrict__ out_loss) {
  __shared__ double sred[4];
  int t = threadIdx.x;
  double s = 0.0;
  for (int i = t; i < 2048; i += 256) s += bs[i];
  #pragma unroll
  for (int o = 32; o > 0; o >>= 1) s += __shfl_down(s, o, 64);
  if ((t & 63) == 0) sred[t >> 6] = s;
  __syncthreads();
  if (t == 0)
    out_loss[0] = (float)(0.25 * (((sred[0] + sred[1]) + (sred[2] + sred[3])) / (double)Q_ELEMS));
}

extern "C" void kernel_launch(void* const* d_in, const int* in_sizes, int n_in,
                              void* d_out, int out_size, void* d_ws, size_t ws_size,
                              hipStream_t stream) {
  const float* x = (const float*)d_in[0];
  const float* e = (const float*)d_in[1];
  float* out = (float*)d_out;
  float* out_q = out;
  float* out_loss = out + Q_ELEMS;
  float* out_idx = out + Q_ELEMS + 1;

  char* ws = (char*)d_ws;
  float* norms = (float*)ws;
  double* bsums = (double*)(ws + 2048);
  unsigned* bitmap = (unsigned*)(ws + 20480);
  unsigned short* e16 = (unsigned short*)(ws + 36864);
  int use_ws = (ws_size >= 299008) ? 1 : 0;

  vq_prep<<<K_CODES, 256, 0, stream>>>(e, norms, e16, bitmap, use_ws);
  if (use_ws)
    vq_main<1><<<N_ROWS / 64, 256, 0, stream>>>(x, e, norms, e16, out_q, out_idx, bsums, bitmap);
  else
    vq_main<0><<<N_ROWS / 64, 256, 0, stream>>>(x, e, norms, e16, out_q, out_idx, bsums, bitmap);
  vq_fixup<<<N_ROWS / 64, 64, 0, stream>>>(x, e, norms, bitmap, out_q, out_idx);
  vq_final<<<1, 256, 0, stream>>>(bsums, out_loss);
}